// Round 7
// baseline (318.371 us; speedup 1.0000x reference)
//
#include <hip/hip_runtime.h>

typedef __bf16 bf16;
typedef __attribute__((ext_vector_type(4))) __bf16 bf16x4;
typedef __attribute__((ext_vector_type(8))) __bf16 bf16x8;
typedef __attribute__((ext_vector_type(16))) float f32x16;

__device__ __forceinline__ void gload_lds16(const void* g, void* l) {
  __builtin_amdgcn_global_load_lds(
      (const __attribute__((address_space(1))) unsigned int*)(unsigned long long)g,
      (__attribute__((address_space(3))) unsigned int*)(unsigned long long)l,
      16, 0, 0);
}

// ---------------- cast fp32 -> bf16 (x4 vectorized) ----------------
__global__ void cast_f32_bf16(const float* __restrict__ in, bf16* __restrict__ out, int n4) {
  int i = blockIdx.x * blockDim.x + threadIdx.x;
  if (i >= n4) return;
  float4 v = reinterpret_cast<const float4*>(in)[i];
  bf16x4 o;
  o[0] = (bf16)v.x; o[1] = (bf16)v.y; o[2] = (bf16)v.z; o[3] = (bf16)v.w;
  reinterpret_cast<bf16x4*>(out)[i] = o;
}

// ------- transpose+cast: V (rows x cols, f32) -> VT (cols x rows, bf16), batched -------
__global__ void transpose_cast(const float* __restrict__ V, bf16* __restrict__ VT,
                               int rows, int cols) {
  __shared__ bf16 tile[64][65];
  const int b = blockIdx.z;
  const float* Vb = V + (long)b * rows * cols;
  bf16* VTb = VT + (long)b * rows * cols;
  const int d0 = blockIdx.x * 64;
  const int k0 = blockIdx.y * 64;
  const int t = threadIdx.x;
  const int r = t >> 4;
  const int c4 = (t & 15) * 4;
#pragma unroll
  for (int p = 0; p < 4; ++p) {
    float4 v = *reinterpret_cast<const float4*>(&Vb[(long)(k0 + p * 16 + r) * cols + d0 + c4]);
    tile[p * 16 + r][c4 + 0] = (bf16)v.x;
    tile[p * 16 + r][c4 + 1] = (bf16)v.y;
    tile[p * 16 + r][c4 + 2] = (bf16)v.z;
    tile[p * 16 + r][c4 + 3] = (bf16)v.w;
  }
  __syncthreads();
#pragma unroll
  for (int p = 0; p < 4; ++p) {
    const int dd = p * 16 + r;
    bf16x4 o;
    o[0] = tile[c4 + 0][dd];
    o[1] = tile[c4 + 1][dd];
    o[2] = tile[c4 + 2][dd];
    o[3] = tile[c4 + 3][dd];
    *reinterpret_cast<bf16x4*>(&VTb[(long)(d0 + dd) * rows + k0 + c4]) = o;
  }
}

// ---------------- in-place row softmax, row length 2048, bf16 ----------------
__global__ void softmax_rows(bf16* __restrict__ S) {
  const long row = blockIdx.x;
  bf16* p = S + row * 2048;
  const int t = threadIdx.x;
  const int wid = t >> 6;
  const int lane = t & 63;
  bf16x8 v = *reinterpret_cast<bf16x8*>(p + t * 8);
  float f[8];
  float m = -3.0e38f;
#pragma unroll
  for (int j = 0; j < 8; ++j) { f[j] = (float)v[j]; m = fmaxf(m, f[j]); }
#pragma unroll
  for (int off = 32; off >= 1; off >>= 1) m = fmaxf(m, __shfl_xor(m, off));
  __shared__ float redm[4], reds[4];
  if (lane == 0) redm[wid] = m;
  __syncthreads();
  m = fmaxf(fmaxf(redm[0], redm[1]), fmaxf(redm[2], redm[3]));
  float s = 0.f;
#pragma unroll
  for (int j = 0; j < 8; ++j) { f[j] = __expf(f[j] - m); s += f[j]; }
#pragma unroll
  for (int off = 32; off >= 1; off >>= 1) s += __shfl_xor(s, off);
  if (lane == 0) reds[wid] = s;
  __syncthreads();
  s = reds[0] + reds[1] + reds[2] + reds[3];
  const float inv = 1.0f / s;
  bf16x8 o;
#pragma unroll
  for (int j = 0; j < 8; ++j) o[j] = (bf16)(f[j] * inv);
  *reinterpret_cast<bf16x8*>(p + t * 8) = o;
}

// -------- B^T GEMM, 256x256 tile, BK=64, mfma_32x32x16, counted-vmcnt 2-phase ---------
// 512 threads = 8 waves (2 M x 4 N); wave owns 128x64 output = 4m x 2n frags of 32x32
// (acc f32x16[4][2] = 128 regs). LDS: [2buf][2op][2kh][256][32] bf16 = 128 KiB.
// Per K-tile, 2 phases (kh = k-half 0/1), each:
//   {12 ds_read_b128 (A 8 + B 4) | stage half kh of BOTH ops for kt+1 (4 gloads)
//    -> vmcnt(4) [drains the half-group staged ONE phase earlier, i.e. what the NEXT
//       phase reads -- never drains the just-issued group] -> s_barrier -> lgkmcnt(0)
//    -> setprio(1) 16 MFMA setprio(0) -> s_barrier}
// Hazards (verified ordering, same as R4): reads target halves drained 1 phase ago and
// published by that phase's barrier; stage overwrites a buf whose readers finished
// before the previous phase's closing barrier.
// XOR chunk swizzle (R4/R5-verified 0 conflicts): physical 16B-chunk = kc ^ ((row>>1)&3).
// 32-row fragment reads re-derived on this swizzle: 64 lanes cover 32 rows x 2 chunks,
// uniform 2 lanes/bank -> conflict-free (bank = 16*(row&1) + 4*chunk).
// MODE 0: bf16 out + bias (bz selects bias0/bias1); MODE 1: bf16 * (1/scale); MODE 2: f32.

#define BARRIER __builtin_amdgcn_s_barrier()
#define LGKM0                                              \
  do {                                                     \
    asm volatile("s_waitcnt lgkmcnt(0)" ::: "memory");     \
    __builtin_amdgcn_sched_barrier(0);                     \
  } while (0)
#define VM4                                                \
  do {                                                     \
    asm volatile("s_waitcnt vmcnt(4)" ::: "memory");       \
    __builtin_amdgcn_sched_barrier(0);                     \
  } while (0)
#define VM0                                                \
  do {                                                     \
    asm volatile("s_waitcnt vmcnt(0)" ::: "memory");       \
    __builtin_amdgcn_sched_barrier(0);                     \
  } while (0)

// stage k-half kh of BOTH ops of the tile at global k-offset ko into buf (4 gloads)
#define STAGEH(buf, kh, ko)                                     \
  {                                                             \
    bf16* lA_ = ldsw + ((buf) * 4 + (kh)) * 8192;               \
    bf16* lB_ = ldsw + ((buf) * 4 + 2 + (kh)) * 8192;           \
    const long g_ = (ko) + (kh) * 32;                           \
    gload_lds16(gA + g_, lA_);                                  \
    gload_lds16(gA + g_ + rK128, lA_ + 4096);                   \
    gload_lds16(gB + g_, lB_);                                  \
    gload_lds16(gB + g_ + rK128, lB_ + 4096);                   \
  }

// fragment reads for phase kh of buf: A[m 0-3][s 0-1], B[n 0-1][s 0-1]
#define LOADP(buf, kh)                                                         \
  _Pragma("unroll") for (int m_ = 0; m_ < 4; ++m_) {                           \
    const bf16* p_ = aB32 + ((buf) * 4 + (kh)) * 8192 + m_ * 1024;             \
    a[m_][0] = *reinterpret_cast<const bf16x8*>(p_ + pk0);                     \
    a[m_][1] = *reinterpret_cast<const bf16x8*>(p_ + pk1);                     \
  }                                                                            \
  _Pragma("unroll") for (int n_ = 0; n_ < 2; ++n_) {                           \
    const bf16* p_ = bB32 + ((buf) * 4 + 2 + (kh)) * 8192 + n_ * 1024;         \
    b[n_][0] = *reinterpret_cast<const bf16x8*>(p_ + pk0);                     \
    b[n_][1] = *reinterpret_cast<const bf16x8*>(p_ + pk1);                     \
  }

#define MFMAP32                                                                \
  _Pragma("unroll") for (int m_ = 0; m_ < 4; ++m_)                             \
  _Pragma("unroll") for (int n_ = 0; n_ < 2; ++n_) {                           \
    acc[m_][n_] = __builtin_amdgcn_mfma_f32_32x32x16_bf16(                     \
        a[m_][0], b[n_][0], acc[m_][n_], 0, 0, 0);                             \
    acc[m_][n_] = __builtin_amdgcn_mfma_f32_32x32x16_bf16(                     \
        a[m_][1], b[n_][1], acc[m_][n_], 0, 0, 0);                             \
  }

template <int MODE>
__global__ __launch_bounds__(512, 2)
void gemm_bt(const bf16* __restrict__ A, const bf16* __restrict__ Bm,
             const float* __restrict__ bias0, const float* __restrict__ bias1,
             void* __restrict__ Cvoid, const int* __restrict__ scale_ptr,
             int N, int K, long sA, long sB, long sC) {
  __shared__ bf16 lds[8][256][32];  // [buf*4 + op*2 + kh][row][32k] = 128 KiB
  const int t = threadIdx.x;
  const int lane = t & 63;
  const int wid = t >> 6;   // 0..7
  const int wm = wid >> 2;  // 0..1
  const int wn = wid & 3;   // 0..3

  // XCD-aware bijective swizzle (all grids here have nwg % 8 == 0)
  const int gx = gridDim.x, gy = gridDim.y;
  const int nwg = gx * gy * gridDim.z;
  int id = blockIdx.x + gx * (blockIdx.y + gy * blockIdx.z);
  {
    const int cpx = nwg >> 3;
    id = (id & 7) * cpx + (id >> 3);
  }
  const int bx = id % gx;
  const int by = (id / gx) % gy;
  const int bz = id / (gx * gy);

  const bf16* Ab = A + (long)bz * sA;
  const bf16* Bb = Bm + (long)bz * sB;
  const int tile_m = by * 256;
  const int tile_n = bx * 256;

  // staging: half-tile = [256][32] = 1024 x 16B chunks (4/row); thread t covers chunk t
  // (row=t>>2, kc=t&3) and chunk t+512 (row+128; same swizzle, 128%4==0).
  // Source pre-swizzled: global kc = (t&3) ^ ((row>>1)&3). LDS dest linear == row-major.
  const int srow = t >> 2;                              // 0..127
  const int soff = (((t & 3) ^ ((t >> 3) & 3)) << 3);   // swizzled elem offset in row
  const bf16* gA = Ab + (long)(tile_m + srow) * K + soff;
  const bf16* gB = Bb + (long)(tile_n + srow) * K + soff;
  const long rK128 = (long)K << 7;   // +128 rows
  bf16* const ldsw = &lds[0][0][0] + wid * 512;  // wave-uniform dest (+HW lane*16B)

  // 32x32x16 fragment reads: lane covers row frow32=lane&31 of a 32-row block,
  // k-span (lane>>5)*8 within a 16-wide k-slice. Logical chunk for k-slice parity s:
  // s*2 + (lane>>5); physical = logical ^ ((frow32>>1)&3) -> two lane-constant offsets.
  const int frow32 = lane & 31;
  const int kcL = lane >> 5;                     // 0..1
  const int sw32 = (frow32 >> 1) & 3;
  const int pk0 = ((kcL ^ sw32) << 3);           // k-slices 0,2 (chunk pair {0,1})
  const int pk1 = (((2 + kcL) ^ sw32) << 3);     // k-slices 1,3 (chunk pair {2,3})
  const bf16* aB32 = &lds[0][0][0] + (wm * 128 + frow32) * 32;
  const bf16* bB32 = &lds[0][0][0] + (wn * 64 + frow32) * 32;

  bf16x8 a[4][2], b[2][2];
  f32x16 acc[4][2] = {};

  // prologue: stage tile 0 (both halves, 8 gloads); drain H0 group; publish
  STAGEH(0, 0, 0)
  STAGEH(0, 1, 0)
  VM4;       // 8 outstanding -> drains H0 group (A.H0 + B.H0)
  BARRIER;

  const int NK = K >> 6;
  int c = 0;
  for (int kt = 0; kt < NK; ++kt, c ^= 1) {
    const long ko = (long)((kt + 1 < NK) ? (kt + 1) : kt) << 6;  // last iter: dead stage
    // phase 0 (kh=0): reads H0 of c (drained+published 1 phase ago)
    LOADP(c, 0)
    STAGEH(c ^ 1, 0, ko)
    VM4;     // drains H1 group of tile kt (staged last phase of kt-1) for phase 1
    BARRIER;
    LGKM0;
    __builtin_amdgcn_s_setprio(1);
    MFMAP32
    __builtin_amdgcn_s_setprio(0);
    BARRIER;
    // phase 1 (kh=1)
    LOADP(c, 1)
    STAGEH(c ^ 1, 1, ko)
    VM4;     // drains H0 group of tile kt+1 for next tile's phase 0
    BARRIER;
    LGKM0;
    __builtin_amdgcn_s_setprio(1);
    MFMAP32
    __builtin_amdgcn_s_setprio(0);
    BARRIER;
  }
  VM0;  // retire dead stages before endpgm

  float scl = 1.0f;
  if (MODE == 1) {
    const int iv = scale_ptr[0];
    const float fv = __int_as_float(iv);
    const float sv = (iv > 0 && iv < (1 << 20)) ? (float)iv : fv;
    scl = 1.0f / sv;
  }
  // 32x32 C/D layout (verified m74/m101): col=lane&31, row=(reg&3)+8*(reg>>2)+4*(lane>>5)
  const int rb = tile_m + wm * 128 + ((lane >> 5) << 2);
  const int cb = tile_n + wn * 64 + (lane & 31);
  if (MODE == 2) {
    float* C = reinterpret_cast<float*>(Cvoid) + (long)bz * sC;
#pragma unroll
    for (int mf = 0; mf < 4; ++mf)
#pragma unroll
      for (int nf = 0; nf < 2; ++nf)
#pragma unroll
        for (int rg = 0; rg < 16; ++rg) {
          const int row = rb + mf * 32 + (rg & 3) + ((rg >> 2) << 3);
          C[(long)row * N + cb + nf * 32] = acc[mf][nf][rg];
        }
  } else {
    bf16* C = reinterpret_cast<bf16*>(Cvoid) + (long)bz * sC;
    const float* bias = (MODE == 0) ? (bz ? bias1 : bias0) : nullptr;
#pragma unroll
    for (int nf = 0; nf < 2; ++nf) {
      const int col = cb + nf * 32;
      const float bv = (MODE == 0) ? bias[col] : 0.0f;
#pragma unroll
      for (int mf = 0; mf < 4; ++mf)
#pragma unroll
        for (int rg = 0; rg < 16; ++rg) {
          const int row = rb + mf * 32 + (rg & 3) + ((rg >> 2) << 3);
          C[(long)row * N + col] = (bf16)(acc[mf][nf][rg] * scl + bv);
        }
    }
  }
}

extern "C" void kernel_launch(void* const* d_in, const int* in_sizes, int n_in,
                              void* d_out, int out_size, void* d_ws, size_t ws_size,
                              hipStream_t stream) {
  (void)in_sizes; (void)n_in; (void)out_size; (void)ws_size;
  const float* query = (const float*)d_in[0];
  const float* key   = (const float*)d_in[1];
  const float* value = (const float*)d_in[2];
  const float* Wq    = (const float*)d_in[3];
  const float* bq    = (const float*)d_in[4];
  const float* Wk    = (const float*)d_in[5];
  const float* bk    = (const float*)d_in[6];
  const int*   scale = (const int*)d_in[7];

  const int L = 2048, D = 1024;
  // ws layout (bytes):
  //   [0,   64M): q_cast(32M) + k_cast(32M), later reused as S/P (8*2048*2048 bf16 = 64M exactly)
  //   [64M, 96M): Qp   [96M,128M): Kp   [128M,160M): VT   [160M,162M): Wq_b  [162M,164M): Wk_b
  char* ws = (char*)d_ws;
  bf16* q_cast = (bf16*)ws;
  bf16* k_cast = q_cast + (long)16384 * 1024;
  bf16* S      = q_cast;
  bf16* Qp     = (bf16*)(ws + (size_t)67108864);
  bf16* Kp     = (bf16*)(ws + (size_t)100663296);
  bf16* VT     = (bf16*)(ws + (size_t)134217728);
  bf16* Wqb    = (bf16*)(ws + (size_t)167772160);
  bf16* Wkb    = (bf16*)(ws + (size_t)169869312);

  cast_f32_bf16<<<16384, 256, 0, stream>>>(query, q_cast, 4194304);
  cast_f32_bf16<<<16384, 256, 0, stream>>>(key,   k_cast, 4194304);
  cast_f32_bf16<<<1024,  256, 0, stream>>>(Wq, Wqb, 262144);
  cast_f32_bf16<<<1024,  256, 0, stream>>>(Wk, Wkb, 262144);
  transpose_cast<<<dim3(16, 32, 8), 256, 0, stream>>>(value, VT, 2048, 1024);

  // projections (fused Q+K in one launch; z=0 -> Q, z=1 -> K): M=16384, N=1024, K=1024
  gemm_bt<0><<<dim3(4, 64, 2), 512, 0, stream>>>(q_cast, Wqb, bq, bk, Qp, nullptr,
                                                 1024, 1024,
                                                 16777216L, 1048576L, 16777216L);
  // scores: S[b] = (Qp[b] @ Kp[b]^T) / scale   (M=N=2048, K=1024, batched over 8)
  gemm_bt<1><<<dim3(8, 8, 8), 512, 0, stream>>>(Qp, Kp, nullptr, nullptr, S, scale,
                                                2048, 1024,
                                                (long)L * D, (long)L * D, (long)L * L);
  softmax_rows<<<16384, 256, 0, stream>>>(S);
  // out: O[b] = P[b] @ VT[b]^T  (M=2048, N=1024, K=2048, f32 out)
  gemm_bt<2><<<dim3(4, 8, 8), 512, 0, stream>>>(S, VT, nullptr, nullptr, d_out, nullptr,
                                                1024, 2048,
                                                (long)L * L, (long)D * L, (long)L * D);
}

// Round 8
// 296.788 us; speedup vs baseline: 1.0727x; 1.0727x over previous
//
#include <hip/hip_runtime.h>

typedef __bf16 bf16;
typedef __attribute__((ext_vector_type(4))) __bf16 bf16x4;
typedef __attribute__((ext_vector_type(8))) __bf16 bf16x8;
typedef __attribute__((ext_vector_type(4))) float f32x4;

__device__ __forceinline__ void gload_lds16(const void* g, void* l) {
  __builtin_amdgcn_global_load_lds(
      (const __attribute__((address_space(1))) unsigned int*)(unsigned long long)g,
      (__attribute__((address_space(3))) unsigned int*)(unsigned long long)l,
      16, 0, 0);
}

// ---------------- cast fp32 -> bf16 (x4 vectorized) -- weights only ----------------
__global__ void cast_f32_bf16(const float* __restrict__ in, bf16* __restrict__ out, int n4) {
  int i = blockIdx.x * blockDim.x + threadIdx.x;
  if (i >= n4) return;
  float4 v = reinterpret_cast<const float4*>(in)[i];
  bf16x4 o;
  o[0] = (bf16)v.x; o[1] = (bf16)v.y; o[2] = (bf16)v.z; o[3] = (bf16)v.w;
  reinterpret_cast<bf16x4*>(out)[i] = o;
}

// ------- transpose+cast: V (rows x cols, f32) -> VT (cols x rows, bf16), batched -------
__global__ void transpose_cast(const float* __restrict__ V, bf16* __restrict__ VT,
                               int rows, int cols) {
  __shared__ bf16 tile[64][65];
  const int b = blockIdx.z;
  const float* Vb = V + (long)b * rows * cols;
  bf16* VTb = VT + (long)b * rows * cols;
  const int d0 = blockIdx.x * 64;
  const int k0 = blockIdx.y * 64;
  const int t = threadIdx.x;
  const int r = t >> 4;
  const int c4 = (t & 15) * 4;
#pragma unroll
  for (int p = 0; p < 4; ++p) {
    float4 v = *reinterpret_cast<const float4*>(&Vb[(long)(k0 + p * 16 + r) * cols + d0 + c4]);
    tile[p * 16 + r][c4 + 0] = (bf16)v.x;
    tile[p * 16 + r][c4 + 1] = (bf16)v.y;
    tile[p * 16 + r][c4 + 2] = (bf16)v.z;
    tile[p * 16 + r][c4 + 3] = (bf16)v.w;
  }
  __syncthreads();
#pragma unroll
  for (int p = 0; p < 4; ++p) {
    const int dd = p * 16 + r;
    bf16x4 o;
    o[0] = tile[c4 + 0][dd];
    o[1] = tile[c4 + 1][dd];
    o[2] = tile[c4 + 2][dd];
    o[3] = tile[c4 + 3][dd];
    *reinterpret_cast<bf16x4*>(&VTb[(long)(d0 + dd) * rows + k0 + c4]) = o;
  }
}

// ---------------- in-place row softmax, row length 2048, bf16 ----------------
__global__ void softmax_rows(bf16* __restrict__ S) {
  const long row = blockIdx.x;
  bf16* p = S + row * 2048;
  const int t = threadIdx.x;
  const int wid = t >> 6;
  const int lane = t & 63;
  bf16x8 v = *reinterpret_cast<bf16x8*>(p + t * 8);
  float f[8];
  float m = -3.0e38f;
#pragma unroll
  for (int j = 0; j < 8; ++j) { f[j] = (float)v[j]; m = fmaxf(m, f[j]); }
#pragma unroll
  for (int off = 32; off >= 1; off >>= 1) m = fmaxf(m, __shfl_xor(m, off));
  __shared__ float redm[4], reds[4];
  if (lane == 0) redm[wid] = m;
  __syncthreads();
  m = fmaxf(fmaxf(redm[0], redm[1]), fmaxf(redm[2], redm[3]));
  float s = 0.f;
#pragma unroll
  for (int j = 0; j < 8; ++j) { f[j] = __expf(f[j] - m); s += f[j]; }
#pragma unroll
  for (int off = 32; off >= 1; off >>= 1) s += __shfl_xor(s, off);
  if (lane == 0) reds[wid] = s;
  __syncthreads();
  s = reds[0] + reds[1] + reds[2] + reds[3];
  const float inv = 1.0f / s;
  bf16x8 o;
#pragma unroll
  for (int j = 0; j < 8; ++j) o[j] = (bf16)(f[j] * inv);
  *reinterpret_cast<bf16x8*>(p + t * 8) = o;
}

// ---------------- B^T GEMM, 256x256 tile, BK=64, 8-phase (R2 core, best measured) ------
// 512 threads = 8 waves (2 M x 4 N), each wave owns a 128x64 output sub-tile.
// LDS [buf2][op2][half2][128][64] bf16 = 128 KiB, XOR chunk swizzle kc^(row&7)
// (R2-measured: 0 bank conflicts, 97.1-97.6 us per 68.7-GFLOP launch).
// MODE 1: bf16 out * (1/scale); MODE 2: f32 out.

#define BARRIER __builtin_amdgcn_s_barrier()
#define LGKM0                                              \
  do {                                                     \
    asm volatile("s_waitcnt lgkmcnt(0)" ::: "memory");     \
    __builtin_amdgcn_sched_barrier(0);                     \
  } while (0)
#define VM0                                                \
  do {                                                     \
    asm volatile("s_waitcnt vmcnt(0)" ::: "memory");       \
    __builtin_amdgcn_sched_barrier(0);                     \
  } while (0)

#define STAGE_A(buf, ko)                                        \
  {                                                             \
    bf16* l_ = ldsd + (buf) * 32768;                            \
    const bf16* g_ = gA + (ko);                                 \
    gload_lds16(g_, l_);                                        \
    gload_lds16(g_ + rK64, l_ + 4096);                          \
    gload_lds16(g_ + rK128, l_ + 8192);                         \
    gload_lds16(g_ + rK128 + rK64, l_ + 12288);                 \
  }
#define STAGE_B(buf, ko)                                        \
  {                                                             \
    bf16* l_ = ldsd + (buf) * 32768 + 16384;                    \
    const bf16* g_ = gB + (ko);                                 \
    gload_lds16(g_, l_);                                        \
    gload_lds16(g_ + rK64, l_ + 4096);                          \
    gload_lds16(g_ + rK128, l_ + 8192);                         \
    gload_lds16(g_ + rK128 + rK64, l_ + 12288);                 \
  }

#define LOADA(buf, mq)                                                        \
  {                                                                           \
    const bf16* p_ = aBase + (buf) * 32768 + (mq) * 4096;                     \
    _Pragma("unroll") for (int m_ = 0; m_ < 4; ++m_) {                        \
      a[m_][0] = *reinterpret_cast<const bf16x8*>(p_ + m_ * 1024 + pk0);      \
      a[m_][1] = *reinterpret_cast<const bf16x8*>(p_ + m_ * 1024 + pk1);      \
    }                                                                         \
  }
#define LOADB(buf, nq)                                                        \
  {                                                                           \
    const bf16* p_ = bBase + (buf) * 32768 + (nq) * 2048;                     \
    _Pragma("unroll") for (int n_ = 0; n_ < 2; ++n_) {                        \
      b[(nq) * 2 + n_][0] = *reinterpret_cast<const bf16x8*>(p_ + n_ * 1024 + pk0); \
      b[(nq) * 2 + n_][1] = *reinterpret_cast<const bf16x8*>(p_ + n_ * 1024 + pk1); \
    }                                                                         \
  }

#define MFMAQ(mq, nq)                                                         \
  _Pragma("unroll") for (int m_ = 0; m_ < 4; ++m_)                            \
  _Pragma("unroll") for (int n_ = 0; n_ < 2; ++n_)                            \
  _Pragma("unroll") for (int ks_ = 0; ks_ < 2; ++ks_)                         \
      acc[(mq) * 4 + m_][(nq) * 2 + n_] =                                     \
          __builtin_amdgcn_mfma_f32_16x16x32_bf16(                            \
              a[m_][ks_], b[(nq) * 2 + n_][ks_],                              \
              acc[(mq) * 4 + m_][(nq) * 2 + n_], 0, 0, 0);

template <int MODE>
__global__ __launch_bounds__(512, 2)
void gemm_bt(const bf16* __restrict__ A, const bf16* __restrict__ Bm,
             void* __restrict__ Cvoid, const int* __restrict__ scale_ptr,
             int N, int K, long sA, long sB, long sC) {
  __shared__ bf16 lds[2][2][2][128][64];  // [buf][opA/B][half][row][64k] = 128 KiB
  const int t = threadIdx.x;
  const int lane = t & 63;
  const int wid = t >> 6;   // 0..7
  const int wm = wid >> 2;  // 0..1
  const int wn = wid & 3;   // 0..3

  // XCD-aware bijective swizzle (all grids here have nwg % 8 == 0)
  const int gx = gridDim.x, gy = gridDim.y;
  const int nwg = gx * gy * gridDim.z;
  int id = blockIdx.x + gx * (blockIdx.y + gy * blockIdx.z);
  {
    const int cpx = nwg >> 3;
    id = (id & 7) * cpx + (id >> 3);
  }
  const int bx = id % gx;
  const int by = (id / gx) % gy;
  const int bz = id / (gx * gy);

  const bf16* Ab = A + (long)bz * sA;
  const bf16* Bb = Bm + (long)bz * sB;
  const int tile_m = by * 256;
  const int tile_n = bx * 256;

  // staging: half-tile = [128][64] = 1024 x 16B chunks; thread t covers chunk t
  // (row=t>>3, kc=t&7) and chunk t+512 (row+64). Source pre-swizzled: global
  // chunk = kc ^ (row&7). Dest linear: elem = chunk*8 (wave-uniform + lane*16B).
  const int srow = t >> 3;
  const int skc = t & 7;
  const int soff = ((skc ^ (srow & 7)) << 3);
  const bf16* gA = Ab + (long)(tile_m + srow) * K + soff;
  const bf16* gB = Bb + (long)(tile_n + srow) * K + soff;
  const long rK64 = (long)K << 6;    // +64 rows
  const long rK128 = (long)K << 7;   // +128 rows (half stride)
  bf16* const ldsd = &lds[0][0][0][0][0] + wid * 512;

  // fragment reads: lane reads row frow=lane&15 of its half, logical k-chunk
  // ks*4+(lane>>4); physical chunk = logical ^ (row&7) = logical ^ (lane&7).
  const int frow = lane & 15;
  const int pk0 = (((lane >> 4) ^ (lane & 7))) << 3;
  const int pk1 = (((4 | (lane >> 4)) ^ (lane & 7))) << 3;
  const bf16* aBase = &lds[0][0][wm][frow][0];
  const bf16* bBase = &lds[0][1][wn >> 1][(wn & 1) * 64 + frow][0];

  bf16x8 a[4][2], b[4][2];
  f32x4 acc[8][4] = {};

  // prologue: stage tile 0 fully, drain once, sync
  STAGE_A(0, 0)
  STAGE_B(0, 0)
  VM0;
  BARRIER;

  const int NK = K >> 6;
  int c = 0;
  for (int kt = 0; kt < NK - 1; ++kt, c ^= 1) {
    const long ko = (long)(kt + 1) << 6;
    // P0: quadrant (0,0); prefetch A of kt+1
    LOADA(c, 0)
    LOADB(c, 0)
    STAGE_A(c ^ 1, ko)
    BARRIER;
    LGKM0;
    __builtin_amdgcn_s_setprio(1);
    MFMAQ(0, 0)
    __builtin_amdgcn_s_setprio(0);
    BARRIER;
    // P1: quadrant (0,1); prefetch B of kt+1
    LOADB(c, 1)
    STAGE_B(c ^ 1, ko)
    BARRIER;
    LGKM0;
    __builtin_amdgcn_s_setprio(1);
    MFMAQ(0, 1)
    __builtin_amdgcn_s_setprio(0);
    BARRIER;
    // P2: quadrant (1,0)
    LOADA(c, 1)
    BARRIER;
    LGKM0;
    __builtin_amdgcn_s_setprio(1);
    MFMAQ(1, 0)
    __builtin_amdgcn_s_setprio(0);
    BARRIER;
    // P3: boundary — drain kt+1's loads, sync, last quadrant
    VM0;
    BARRIER;
    __builtin_amdgcn_s_setprio(1);
    MFMAQ(1, 1)
    __builtin_amdgcn_s_setprio(0);
  }
  // peeled last tile: pure compute from buf c
  LOADA(c, 0)
  LOADB(c, 0)
  LOADB(c, 1)
  MFMAQ(0, 0)
  MFMAQ(0, 1)
  LOADA(c, 1)
  MFMAQ(1, 0)
  MFMAQ(1, 1)

  float scl = 1.0f;
  if (MODE == 1) {
    const int iv = scale_ptr[0];
    const float fv = __int_as_float(iv);
    const float sv = (iv > 0 && iv < (1 << 20)) ? (float)iv : fv;
    scl = 1.0f / sv;
  }
  // C/D layout (verified m89/m91): col=lane&15, row=(lane>>4)*4+reg
  const int rb = tile_m + wm * 128 + ((lane >> 4) << 2);
  const int cb = tile_n + wn * 64 + (lane & 15);
  if (MODE == 2) {
    float* C = reinterpret_cast<float*>(Cvoid) + (long)bz * sC;
#pragma unroll
    for (int mf = 0; mf < 8; ++mf)
#pragma unroll
      for (int nf = 0; nf < 4; ++nf)
#pragma unroll
        for (int r = 0; r < 4; ++r)
          C[(long)(rb + mf * 16 + r) * N + (cb + nf * 16)] = acc[mf][nf][r];
  } else {
    bf16* C = reinterpret_cast<bf16*>(Cvoid) + (long)bz * sC;
#pragma unroll
    for (int nf = 0; nf < 4; ++nf) {
      const int col = cb + nf * 16;
#pragma unroll
      for (int mf = 0; mf < 8; ++mf)
#pragma unroll
        for (int r = 0; r < 4; ++r)
          C[(long)(rb + mf * 16 + r) * N + col] = (bf16)(acc[mf][nf][r] * scl);
    }
  }
}

// -------- projection GEMM with fused f32->bf16 cast of A (q/k raw inputs) -----------
// C[m][n] = sum_k A_f32[m][k] * W_bf16[n][k] + bias[n]; z selects (query,Wq,bq,Qp) vs
// (key,Wk,bk,Kp). 128x256 tile, BK=32, 512 thr = 8 waves (2Mx4N), acc[4][4], R5 geometry
// (52 VGPR class -> 2 blocks/CU TLP). A is REG-STAGED: 2x float4 load issued at loop
// top (T14 issue-early), cvt+1x ds_write_b128 after the MFMA burst (write-late); the
// swizzled LDS dest is legal here (not global_load_lds). B via gload_lds, pre-swizzled
// source. Swizzle = R4/R5-verified [*][32] scheme: physical chunk = kc ^ ((row>>1)&3).
__global__ __launch_bounds__(512, 2)
void gemm_proj(const float* __restrict__ Aq, const float* __restrict__ Ak,
               const bf16* __restrict__ Wb, const float* __restrict__ bias0,
               const float* __restrict__ bias1, bf16* __restrict__ Cout,
               int N, int K, long sB, long sC) {
  __shared__ bf16 lds[2][12288];  // per buf: A 128x32 (4096 el) + B 256x32 (8192 el)
  const int t = threadIdx.x;
  const int lane = t & 63;
  const int wid = t >> 6;
  const int wm = wid >> 2;
  const int wn = wid & 3;

  const int gx = gridDim.x, gy = gridDim.y;
  const int nwg = gx * gy * gridDim.z;
  int id = blockIdx.x + gx * (blockIdx.y + gy * blockIdx.z);
  {
    const int cpx = nwg >> 3;
    id = (id & 7) * cpx + (id >> 3);
  }
  const int bx = id % gx;
  const int by = (id / gx) % gy;
  const int bz = id / (gx * gy);

  const float* Af = bz ? Ak : Aq;
  const bf16* Bb = Wb + (long)bz * sB;
  const int tile_m = by * 128;
  const int tile_n = bx * 256;

  // A reg-staging: [128][32] = 512 chunks, thread t = chunk t: row=t>>2, kc=t&3.
  // f32 source: 8 floats at k = kc*8 (two float4). ds_write dest: swizzled chunk.
  const int arow = t >> 2;
  const int akc = t & 3;
  const float* gAf = Af + (long)(tile_m + arow) * K + akc * 8;
  bf16* const wA = &lds[0][0] + arow * 32 + (((akc ^ ((t >> 3) & 3))) << 3);

  // B staging via gload_lds: [256][32] = 1024 chunks, thread t covers chunks t, t+512
  // (rows srow, srow+128); source pre-swizzled, dest linear (== row-major).
  const int srow = t >> 2;
  const int soff = (((t & 3) ^ ((t >> 3) & 3)) << 3);
  const bf16* gB = Bb + (long)(tile_n + srow) * K + soff;
  const long rK128 = (long)K << 7;
  bf16* const ldsB = &lds[0][4096] + wid * 512;  // wave-uniform (+HW lane*16B)

  // fragment reads (R5-verified 0-conflict): row = base + frow, phys chunk lane-const.
  const int frow = lane & 15;
  const int pko = (((lane >> 4) ^ ((lane >> 1) & 3)) << 3);
  const bf16* aB = &lds[0][0] + (wm * 64 + frow) * 32 + pko;
  const bf16* bB = &lds[0][4096] + (wn * 64 + frow) * 32 + pko;

  bf16x8 a[4], b[4];
  f32x4 acc[4][4] = {};

  // prologue: tile 0 -> buf 0
  {
    float4 p0 = *reinterpret_cast<const float4*>(gAf);
    float4 p1 = *reinterpret_cast<const float4*>(gAf + 4);
    gload_lds16(gB, ldsB);
    gload_lds16(gB + rK128, ldsB + 4096);
    bf16x8 w;
    w[0] = (bf16)p0.x; w[1] = (bf16)p0.y; w[2] = (bf16)p0.z; w[3] = (bf16)p0.w;
    w[4] = (bf16)p1.x; w[5] = (bf16)p1.y; w[6] = (bf16)p1.z; w[7] = (bf16)p1.w;
    *reinterpret_cast<bf16x8*>(wA) = w;
    __syncthreads();
  }

  const int NK = K >> 5;
  int c = 0;
  for (int kt = 0; kt < NK - 1; ++kt, c ^= 1) {
    const long ko = (long)(kt + 1) << 5;
    // issue next tile's A loads + B gloads FIRST (latency hides under MFMA)
    float4 n0 = *reinterpret_cast<const float4*>(gAf + ko);
    float4 n1 = *reinterpret_cast<const float4*>(gAf + ko + 4);
    gload_lds16(gB + ko, ldsB + (c ^ 1) * 12288);
    gload_lds16(gB + ko + rK128, ldsB + (c ^ 1) * 12288 + 4096);
    // compute current tile from buf c
#pragma unroll
    for (int n_ = 0; n_ < 4; ++n_)
      b[n_] = *reinterpret_cast<const bf16x8*>(bB + c * 12288 + n_ * 512);
#pragma unroll
    for (int m_ = 0; m_ < 4; ++m_)
      a[m_] = *reinterpret_cast<const bf16x8*>(aB + c * 12288 + m_ * 512);
#pragma unroll
    for (int m_ = 0; m_ < 4; ++m_)
#pragma unroll
      for (int n_ = 0; n_ < 4; ++n_)
        acc[m_][n_] = __builtin_amdgcn_mfma_f32_16x16x32_bf16(a[m_], b[n_], acc[m_][n_], 0, 0, 0);
    // write-late: cast + single ds_write into buf c^1 (compiler waits on n0/n1 here)
    {
      bf16x8 w;
      w[0] = (bf16)n0.x; w[1] = (bf16)n0.y; w[2] = (bf16)n0.z; w[3] = (bf16)n0.w;
      w[4] = (bf16)n1.x; w[5] = (bf16)n1.y; w[6] = (bf16)n1.z; w[7] = (bf16)n1.w;
      *reinterpret_cast<bf16x8*>(wA + (c ^ 1) * 12288) = w;
    }
    __syncthreads();  // drains B gloads (vmcnt 0) + publishes ds_writes + read-complete
  }
  // peeled last tile
#pragma unroll
  for (int n_ = 0; n_ < 4; ++n_)
    b[n_] = *reinterpret_cast<const bf16x8*>(bB + c * 12288 + n_ * 512);
#pragma unroll
  for (int m_ = 0; m_ < 4; ++m_)
    a[m_] = *reinterpret_cast<const bf16x8*>(aB + c * 12288 + m_ * 512);
#pragma unroll
  for (int m_ = 0; m_ < 4; ++m_)
#pragma unroll
    for (int n_ = 0; n_ < 4; ++n_)
      acc[m_][n_] = __builtin_amdgcn_mfma_f32_16x16x32_bf16(a[m_], b[n_], acc[m_][n_], 0, 0, 0);

  // epilogue: bf16 out + bias (bz selects)
  const float* bias = bz ? bias1 : bias0;
  const int rb = tile_m + wm * 64 + ((lane >> 4) << 2);
  const int cb = tile_n + wn * 64 + (lane & 15);
  bf16* C = Cout + (long)bz * sC;
#pragma unroll
  for (int nf = 0; nf < 4; ++nf) {
    const int col = cb + nf * 16;
    const float bv = bias[col];
#pragma unroll
    for (int mf = 0; mf < 4; ++mf)
#pragma unroll
      for (int r = 0; r < 4; ++r)
        C[(long)(rb + mf * 16 + r) * N + col] = (bf16)(acc[mf][nf][r] + bv);
  }
}

extern "C" void kernel_launch(void* const* d_in, const int* in_sizes, int n_in,
                              void* d_out, int out_size, void* d_ws, size_t ws_size,
                              hipStream_t stream) {
  (void)in_sizes; (void)n_in; (void)out_size; (void)ws_size;
  const float* query = (const float*)d_in[0];
  const float* key   = (const float*)d_in[1];
  const float* value = (const float*)d_in[2];
  const float* Wq    = (const float*)d_in[3];
  const float* bq    = (const float*)d_in[4];
  const float* Wk    = (const float*)d_in[5];
  const float* bk    = (const float*)d_in[6];
  const int*   scale = (const int*)d_in[7];

  const int L = 2048, D = 1024;
  // ws layout (bytes):
  //   [0,   64M): S/P (8*2048*2048 bf16 = 64M exactly)
  //   [64M, 96M): Qp   [96M,128M): Kp (= Qp + 16777216 elems)   [128M,160M): VT
  //   [160M,162M): Wq_b  [162M,164M): Wk_b (= Wqb + 1048576 elems)
  char* ws = (char*)d_ws;
  bf16* S      = (bf16*)ws;
  bf16* Qp     = (bf16*)(ws + (size_t)67108864);
  bf16* Kp     = (bf16*)(ws + (size_t)100663296);
  bf16* VT     = (bf16*)(ws + (size_t)134217728);
  bf16* Wqb    = (bf16*)(ws + (size_t)167772160);
  bf16* Wkb    = (bf16*)(ws + (size_t)169869312);

  cast_f32_bf16<<<1024, 256, 0, stream>>>(Wq, Wqb, 262144);
  cast_f32_bf16<<<1024, 256, 0, stream>>>(Wk, Wkb, 262144);
  transpose_cast<<<dim3(16, 32, 8), 256, 0, stream>>>(value, VT, 2048, 1024);

  // projections with fused cast (z=0 -> Q, z=1 -> K): M=16384, N=1024, K=1024
  gemm_proj<<<dim3(4, 128, 2), 512, 0, stream>>>(query, key, Wqb, bq, bk, Qp,
                                                 1024, 1024, 1048576L, 16777216L);
  // scores: S[b] = (Qp[b] @ Kp[b]^T) / scale   (M=N=2048, K=1024, batched over 8)
  gemm_bt<1><<<dim3(8, 8, 8), 512, 0, stream>>>(Qp, Kp, S, scale,
                                                2048, 1024,
                                                (long)L * D, (long)L * D, (long)L * L);
  softmax_rows<<<16384, 256, 0, stream>>>(S);
  // out: O[b] = P[b] @ VT[b]^T  (M=2048, N=1024, K=2048, f32 out)
  gemm_bt<2><<<dim3(4, 8, 8), 512, 0, stream>>>(S, VT, d_out, nullptr,
                                                1024, 2048,
                                                (long)L * L, (long)D * L, (long)L * D);
}